// Round 4
// baseline (603.669 us; speedup 1.0000x reference)
//
#include <hip/hip_runtime.h>
#include <hip/hip_bf16.h>

// ProjectBEV: expand range-image coords (B,H,W,CK,2) into COO sparse-tensor
// index/value arrays, flattened float32 in return order:
//   [0, 6N)        presence_indices [N,6]  = [b, qx, qy, c, h, w]
//   [6N, 7N)       presence_vals    [N]    = 1
//   [7N, 21N)      position_indices [2N,7] = [b, qx, qy, c, h, w, d]
//   [21N, 23N)     position_vals    [2N]   = scaled_xy flat
// n ordered as (B, CK, H, W); input laid out (B, H, W, CK, 2).
//
// R3 lesson: 42 KB LDS + 3 barriers => 3 blocks/CU and every barrier drains
// vmcnt(0) (all global stores) -> store pipe convoys, kernel ~2x roofline.
// R4: stage ONLY (sx,sy) (6 KB), one LDS-only barrier, then a single pure
// streaming-store phase; drain threads recompute index fields from position
// (qx = truncf(sx), b/h block-uniform, c/w from pair index). 8 blocks/CU.

#define BB 16
#define HH 64
#define WW 2048
#define CKK 3
#define NN (BB * CKK * HH * WW)   // 6,291,456

__global__ __launch_bounds__(256) void ProjectBEV_kernel(
    const float* __restrict__ in, float* __restrict__ out) {
    __shared__ float2 sxy[CKK * 256];   // 6 KB: scaled (sx,sy) per item

    const unsigned tid = threadIdx.x;
    const int blk = blockIdx.x;
    const int w0 = (blk & 7) << 8;            // WW/256 = 8 segments
    const int h  = (blk >> 3) & (HH - 1);
    const int b  = blk >> 9;

    const float fb = (float)b, fh = (float)h;
    // ncBase(c) = ((b*3+c)*64+h)*2048 + w0 = nb0 + c*131072
    const int nb0 = (b * 192 + h) * 2048 + w0;

    // ---- phase 1: load 24 B group (3 channels), scale, stage to LDS ----
    const float* g = in + ((b * HH + h) * WW + w0 + (int)tid) * 6;
    float2 sreg[CKK];
    #pragma unroll
    for (int c = 0; c < CKK; ++c) {
        const float2 v = ((const float2*)g)[c];
        sreg[c] = make_float2(v.x * 2.0f + 1.0f, v.y * 2.0f + 81.0f);
        sxy[c * 256 + tid] = sreg[c];
    }
    __syncthreads();   // LDS-only dependency: no global stores issued yet

    // ---- phase 2: pure streaming stores (no further barriers) ----

    // vals: coalesced direct from registers
    #pragma unroll
    for (int c = 0; c < CKK; ++c) {
        const int nc = nb0 + c * 131072 + (int)tid;
        out[6 * NN + nc] = 1.0f;                          // presence_vals
        *(float2*)(out + 21 * NN + 2 * nc) = sreg[c];     // position_vals
    }

    // presence_indices: per channel 256 rows x 6 floats = 768 float2 pairs.
    // pair m = 3*t + sel -> floats (6t+2sel, 6t+2sel+1) of row t:
    //   sel 0:(b,qx) 1:(qy,c) 2:(h,w)
    #pragma unroll
    for (int c = 0; c < CKK; ++c) {
        float2* dst = (float2*)(out + 6 * (nb0 + c * 131072));
        const float fc = (float)c;
        #pragma unroll
        for (int k = 0; k < 3; ++k) {
            const unsigned m = tid + (k << 8);   // [0,768)
            const unsigned t = m / 3u;
            const unsigned sel = m - 3u * t;
            const float2 s = sxy[c * 256 + t];
            const float qx = truncf(s.x), qy = truncf(s.y);  // vals > 0
            const float fw = (float)(w0 + (int)t);
            float2 o;
            o.x = sel == 0 ? fb : (sel == 1 ? qy : fh);
            o.y = sel == 0 ? qx : (sel == 1 ? fc : fw);
            dst[m] = o;
        }
    }

    // position_indices: per channel 256 rows x 14 floats = 1792 float2 pairs.
    // pair m = 7*t + sel:
    //   sel 0:(b,qx) 1:(qy,c) 2:(h,w) 3:(0,b) 4:(qx,qy) 5:(c,h) 6:(w,1)
    #pragma unroll
    for (int c = 0; c < CKK; ++c) {
        float2* dst = (float2*)(out + 7 * NN + 14 * (nb0 + c * 131072));
        const float fc = (float)c;
        #pragma unroll
        for (int k = 0; k < 7; ++k) {
            const unsigned m = tid + (k << 8);   // [0,1792)
            const unsigned t = m / 7u;
            const unsigned sel = m - 7u * t;
            const float2 s = sxy[c * 256 + t];
            const float qx = truncf(s.x), qy = truncf(s.y);
            const float fw = (float)(w0 + (int)t);
            float2 o;
            o.x = sel == 0 ? fb : sel == 1 ? qy : sel == 2 ? fh
                : sel == 3 ? 0.0f : sel == 4 ? qx : sel == 5 ? fc : fw;
            o.y = sel == 0 ? qx : sel == 1 ? fc : sel == 2 ? fw
                : sel == 3 ? fb : sel == 4 ? qy : sel == 5 ? fh : 1.0f;
            dst[m] = o;
        }
    }
}

extern "C" void kernel_launch(void* const* d_in, const int* in_sizes, int n_in,
                              void* d_out, int out_size, void* d_ws, size_t ws_size,
                              hipStream_t stream) {
    const float* in = (const float*)d_in[0];
    float* out = (float*)d_out;
    ProjectBEV_kernel<<<BB * HH * (WW / 256), 256, 0, stream>>>(in, out);  // 8192 blocks
}